// Round 8
// baseline (274.602 us; speedup 1.0000x reference)
//
#include <hip/hip_runtime.h>

// AFGCN: N=50000, E=600000, D=128, L=4. bf16 storage + MFMA, f32 accumulate.
// Round 8: 1024-thr blocks; wave-per-node gather (uniform trip count, 4 rows
// in flight per instr) -> swizzled LDS A-frags -> 16-wave split GEMM + epilogue.

#define D 128

using bf16x8 = __attribute__((ext_vector_type(8))) short;
using f32x4  = __attribute__((ext_vector_type(4))) float;

__device__ inline unsigned short f2b(float f) {
    union { float f; unsigned int u; } v; v.f = f;
    unsigned int u = v.u;
    u += 0x7fffu + ((u >> 16) & 1u);   // round-to-nearest-even
    return (unsigned short)(u >> 16);
}
__device__ inline float b2f_lo(unsigned int u) { return __uint_as_float(u << 16); }
__device__ inline float b2f_hi(unsigned int u) { return __uint_as_float(u & 0xffff0000u); }
__device__ inline unsigned int badd2(unsigned int a, unsigned int b) {
    unsigned short lo = f2b(b2f_lo(a) + b2f_lo(b));
    unsigned short hi = f2b(b2f_hi(a) + b2f_hi(b));
    return (unsigned int)lo | ((unsigned int)hi << 16);
}

// ---------------- CSR build ----------------
__global__ void k_zero_i32(int* __restrict__ p, int n) {
    int i = blockIdx.x * blockDim.x + threadIdx.x;
    if (i < n) p[i] = 0;
}

__global__ void k_hist(const int* __restrict__ dst, int* __restrict__ cnt, int e) {
    int i = blockIdx.x * blockDim.x + threadIdx.x;
    if (i < e) atomicAdd(&cnt[dst[i]], 1);
}

__global__ __launch_bounds__(256) void k_scan_a(const int* __restrict__ cnt,
                                                int* __restrict__ ro,
                                                int* __restrict__ bsum, int n) {
    __shared__ int s[256];
    int tid = threadIdx.x;
    int base = blockIdx.x * 1024 + tid * 4;
    int c[4];
    #pragma unroll
    for (int k = 0; k < 4; ++k) c[k] = (base + k < n) ? cnt[base + k] : 0;
    s[tid] = c[0] + c[1] + c[2] + c[3];
    __syncthreads();
    #pragma unroll
    for (int off = 1; off < 256; off <<= 1) {
        int add = (tid >= off) ? s[tid - off] : 0;
        __syncthreads();
        s[tid] += add;
        __syncthreads();
    }
    int run = (tid == 0) ? 0 : s[tid - 1];
    #pragma unroll
    for (int k = 0; k < 4; ++k) {
        if (base + k < n) ro[base + k] = run;
        run += c[k];
    }
    if (tid == 255) bsum[blockIdx.x] = s[255];
}

__global__ __launch_bounds__(64) void k_scan_b(int* __restrict__ bsum,
                                               int* __restrict__ ro, int nb, int n) {
    int tid = threadIdx.x;
    int orig = (tid < nb) ? bsum[tid] : 0;
    int v = orig;
    #pragma unroll
    for (int off = 1; off < 64; off <<= 1) {
        int u = __shfl_up(v, off, 64);
        if (tid >= off) v += u;
    }
    if (tid < nb) bsum[tid] = v - orig;
    if (tid == 63) ro[n] = v;
}

__global__ __launch_bounds__(256) void k_scan_c(int* __restrict__ ro,
                                                int* __restrict__ cur,
                                                const int* __restrict__ bsum, int n) {
    int base = blockIdx.x * 1024 + threadIdx.x * 4;
    int off = bsum[blockIdx.x];
    #pragma unroll
    for (int k = 0; k < 4; ++k) {
        int i = base + k;
        if (i < n) { int v = ro[i] + off; ro[i] = v; cur[i] = v; }
    }
}

__global__ void k_scatter(const int* __restrict__ src, const int* __restrict__ dst,
                          int* __restrict__ cur, int* __restrict__ ssrc, int e) {
    int i = blockIdx.x * blockDim.x + threadIdx.x;
    if (i < e) {
        int pos = atomicAdd(&cur[dst[i]], 1);
        ssrc[pos] = src[i];
    }
}

// ---------------- prep ----------------
__global__ void k_cvt(const float* __restrict__ in, unsigned short* __restrict__ out,
                      int n8) {
    int i = blockIdx.x * blockDim.x + threadIdx.x;
    if (i >= n8) return;
    float4 a = ((const float4*)in)[i * 2];
    float4 b = ((const float4*)in)[i * 2 + 1];
    ushort4 o0, o1;
    o0.x = f2b(a.x); o0.y = f2b(a.y); o0.z = f2b(a.z); o0.w = f2b(a.w);
    o1.x = f2b(b.x); o1.y = f2b(b.y); o1.z = f2b(b.z); o1.w = f2b(b.w);
    ((ushort4*)out)[i * 2] = o0;
    ((ushort4*)out)[i * 2 + 1] = o1;
}

// Pack Bcat = [Wn;Wr] (256x128) into MFMA fragment order, bf16:
// Bp[layer][ks(8)][nb(8)][lane(64)][8]; n = nb*16+(lane&15), k = ks*32+(lane>>4)*8+j
__global__ void k_pack_B(const float* __restrict__ Wn, const float* __restrict__ Wr,
                         unsigned short* __restrict__ Bp) {
    int t = blockIdx.x * blockDim.x + threadIdx.x;   // < 4*8*8*64
    int lane = t & 63;
    int nb = (t >> 6) & 7;
    int ks = (t >> 9) & 7;
    int l  = t >> 12;
    int ncol = nb * 16 + (lane & 15);
    int k0 = ks * 32 + (lane >> 4) * 8;
    ushort4 lo, hi;
    unsigned short v[8];
    #pragma unroll
    for (int j = 0; j < 8; ++j) {
        int k = k0 + j;
        float f = (k < D) ? Wn[(size_t)l * D * D + k * D + ncol]
                          : Wr[(size_t)l * D * D + (k - D) * D + ncol];
        v[j] = f2b(f);
    }
    lo.x = v[0]; lo.y = v[1]; lo.z = v[2]; lo.w = v[3];
    hi.x = v[4]; hi.y = v[5]; hi.z = v[6]; hi.w = v[7];
    ((ushort4*)Bp)[t * 2] = lo;
    ((ushort4*)Bp)[t * 2 + 1] = hi;
}

#define ACCV(V) do { \
    acc[0] += b2f_lo((V).x); acc[1] += b2f_hi((V).x); \
    acc[2] += b2f_lo((V).y); acc[3] += b2f_hi((V).y); \
    acc[4] += b2f_lo((V).z); acc[5] += b2f_hi((V).z); \
    acc[6] += b2f_lo((V).w); acc[7] += b2f_hi((V).w); } while (0)

// ---------------- fused layer ----------------
// Block = 1024 threads = 16 waves = one 16-row tile (n = 50000 = 3125*16 exact).
// Phase 1: wave w gathers node row0+w. Lanes: e = lane>>4 (edge slot), c = lane&15
//          (16B strip). Uniform trip count (own degree). Cross-e shfl reduce, then
//          e==0 lanes write bf16 strips to aggA[w][strip^(w&7)] (XOR-swizzled).
// Phase 2: wave w: nb = w&7 (16-col block), khalf = w>>3 (0: agg K-steps from LDS,
//          1: h K-steps from global). 4 MFMA each, khalf1 dumps partial C to LDS,
//          khalf0 combines + bias/relu -> tsh transpose -> residual -> store (or fc).
template<bool LAST>
__global__ __launch_bounds__(1024) void k_fused(
        const unsigned short* __restrict__ hb,
        const int* __restrict__ ro,
        const int* __restrict__ ssrc,
        const unsigned short* __restrict__ Bp,     // this layer's 64KB pack
        const float* __restrict__ bias,
        const unsigned short* __restrict__ xb,     // bf16 residual source
        unsigned short* __restrict__ hb_out,
        const float* __restrict__ fcW,
        const float* __restrict__ fcb,
        float* __restrict__ out, int n) {
    __shared__ unsigned short aggA[16][D];         // 4KB, strip-swizzled
    __shared__ float comb[8][64][4];               // 8KB, khalf1 partial C
    __shared__ unsigned short tsh[8][16][16];      // 4KB, epilogue transpose
    __shared__ float fcpart[8][16];                // LAST only

    const int tid  = threadIdx.x;
    const int w    = tid >> 6;                     // wave id = node in tile
    const int lane = tid & 63;
    const int row0 = blockIdx.x * 16;

    // ---- phase 1: gather-aggregate node row0+w ----
    {
        const int e = lane >> 4;                   // 0..3 edge slot
        const int c = lane & 15;                   // 16B strip
        float acc[8] = {0.f, 0.f, 0.f, 0.f, 0.f, 0.f, 0.f, 0.f};
        const int s  = ro[row0 + w];
        const int e2 = ro[row0 + w + 1];
        const unsigned short* hbc = hb + c * 8;
        int j = s + e;
        for (; j + 4 < e2; j += 8) {
            int i0 = ssrc[j];
            int i1 = ssrc[j + 4];
            uint4 v0 = *(const uint4*)(hbc + (size_t)i0 * D);
            uint4 v1 = *(const uint4*)(hbc + (size_t)i1 * D);
            ACCV(v0);
            ACCV(v1);
        }
        if (j < e2) {
            uint4 v = *(const uint4*)(hbc + (size_t)ssrc[j] * D);
            ACCV(v);
        }
        // reduce across the 4 edge slots (lanes xor 16, 32)
        #pragma unroll
        for (int t = 0; t < 8; ++t) {
            acc[t] += __shfl_xor(acc[t], 16, 64);
            acc[t] += __shfl_xor(acc[t], 32, 64);
        }
        if (e == 0) {
            unsigned short af[8];
            #pragma unroll
            for (int t = 0; t < 8; ++t) af[t] = f2b(acc[t]);
            *(uint4*)&aggA[w][((c ^ (w & 7)) << 3)] = *(const uint4*)af;
        }
    }
    __syncthreads();

    // ---- phase 2: split GEMM ----
    const int nb    = w & 7;
    const int khalf = w >> 3;
    const int r = lane & 15;
    const int g = lane >> 4;
    f32x4 acc;
    acc[0] = 0.f; acc[1] = 0.f; acc[2] = 0.f; acc[3] = 0.f;
    const bf16x8* bp = (const bf16x8*)Bp;

    if (khalf == 0) {
        #pragma unroll
        for (int ks = 0; ks < 4; ++ks) {
            int strip = ks * 4 + g;
            bf16x8 afrag = *(const bf16x8*)&aggA[r][((strip ^ (r & 7)) << 3)];
            bf16x8 bfrag = bp[(ks * 8 + nb) * 64 + lane];
            acc = __builtin_amdgcn_mfma_f32_16x16x32_bf16(afrag, bfrag, acc, 0, 0, 0);
        }
    } else {
        const unsigned short* hrow = hb + (size_t)(row0 + r) * D + g * 8;
        #pragma unroll
        for (int ks = 0; ks < 4; ++ks) {
            bf16x8 afrag = *(const bf16x8*)(hrow + ks * 32);
            bf16x8 bfrag = bp[((4 + ks) * 8 + nb) * 64 + lane];
            acc = __builtin_amdgcn_mfma_f32_16x16x32_bf16(afrag, bfrag, acc, 0, 0, 0);
        }
        *(f32x4*)&comb[nb][lane][0] = acc;
    }
    __syncthreads();

    if (khalf == 0) {
        f32x4 t2 = *(const f32x4*)&comb[nb][lane][0];
        acc += t2;

        // bias + relu -> tsh (C layout: col = r, row = g*4 + reg)
        const int colg = nb * 16 + r;
        const float bc = bias[colg];
        #pragma unroll
        for (int reg = 0; reg < 4; ++reg) {
            tsh[nb][g * 4 + reg][r] = f2b(fmaxf(acc[reg] + bc, 0.f));
        }
        // wave-internal LDS dependency (same wave wrote all 16x16) -> no barrier

        const int rr = lane >> 2;                  // 0..15 row
        const int q  = lane & 3;                   // 0..3 col quad
        uint2 tv = *(const uint2*)&tsh[nb][rr][q * 4];
        const size_t goff = (size_t)(row0 + rr) * D + nb * 16 + q * 4;
        uint2 xv = *(const uint2*)(xb + goff);
        if (!LAST) {
            uint2 o;
            o.x = badd2(tv.x, xv.x);
            o.y = badd2(tv.y, xv.y);
            *(uint2*)(hb_out + goff) = o;
        } else {
            const float* fw = fcW + nb * 16 + q * 4;
            float p;
            p  = (b2f_lo(tv.x) + b2f_lo(xv.x)) * fw[0];
            p += (b2f_hi(tv.x) + b2f_hi(xv.x)) * fw[1];
            p += (b2f_lo(tv.y) + b2f_lo(xv.y)) * fw[2];
            p += (b2f_hi(tv.y) + b2f_hi(xv.y)) * fw[3];
            p += __shfl_xor(p, 1, 64);
            p += __shfl_xor(p, 2, 64);
            if (q == 0) fcpart[nb][rr] = p;
        }
    }

    if (LAST) {
        __syncthreads();
        if (w == 0 && lane < 16) {
            float p = 0.f;
            #pragma unroll
            for (int b2 = 0; b2 < 8; ++b2) p += fcpart[b2][lane];
            out[row0 + lane] = p + fcb[0];
        }
    }
}

extern "C" void kernel_launch(void* const* d_in, const int* in_sizes, int n_in,
                              void* d_out, int out_size, void* d_ws, size_t ws_size,
                              hipStream_t stream) {
    const float* x    = (const float*)d_in[0];
    const int*   ei   = (const int*)d_in[1];
    const float* Wn   = (const float*)d_in[2];
    const float* Wr   = (const float*)d_in[3];
    const float* bias = (const float*)d_in[4];
    const float* fcW  = (const float*)d_in[5];
    const float* fcb  = (const float*)d_in[6];
    float* out = (float*)d_out;

    const int n = in_sizes[0] / D;     // 50000
    const int e = in_sizes[1] / 2;     // 600000

    const int* src = ei;
    const int* dst = ei + e;

    // workspace
    char* ws = (char*)d_ws;
    unsigned short* xb   = (unsigned short*)ws;  ws += (size_t)n * D * 2;
    unsigned short* hb_a = (unsigned short*)ws;  ws += (size_t)n * D * 2;
    unsigned short* hb_b = (unsigned short*)ws;  ws += (size_t)n * D * 2;
    unsigned short* Bp   = (unsigned short*)ws;  ws += (size_t)4 * 8 * 8 * 64 * 8 * 2;
    int* ro   = (int*)ws;  ws += (size_t)(n + 1) * 4;
    int* cur  = (int*)ws;  ws += (size_t)n * 4;
    int* ssrc = (int*)ws;  ws += (size_t)e * 4;
    int* bsum = (int*)ws;  ws += 256 * 4;
    (void)ws_size;

    const int nscan = (n + 1023) / 1024;

    // CSR build
    k_zero_i32<<<(n + 255) / 256, 256, 0, stream>>>(cur, n);
    k_hist<<<(e + 255) / 256, 256, 0, stream>>>(dst, cur, e);
    k_scan_a<<<nscan, 256, 0, stream>>>(cur, ro, bsum, n);
    k_scan_b<<<1, 64, 0, stream>>>(bsum, ro, nscan, n);
    k_scan_c<<<nscan, 256, 0, stream>>>(ro, cur, bsum, n);
    k_scatter<<<(e + 255) / 256, 256, 0, stream>>>(src, dst, cur, ssrc, e);

    // prep
    int n8 = n * D / 8;
    k_cvt<<<(n8 + 255) / 256, 256, 0, stream>>>(x, xb, n8);
    k_pack_B<<<(4 * 8 * 8 * 64) / 256, 256, 0, stream>>>(Wn, Wr, Bp);

    const int layer_blocks = (n + 15) / 16;        // 3125 (exact)
    const size_t bpl = (size_t)8 * 8 * 64 * 8;     // ushorts per layer pack

    k_fused<false><<<layer_blocks, 1024, 0, stream>>>(xb, ro, ssrc, Bp,
            bias, xb, hb_a, fcW, fcb, out, n);
    k_fused<false><<<layer_blocks, 1024, 0, stream>>>(hb_a, ro, ssrc, Bp + bpl,
            bias + D, xb, hb_b, fcW, fcb, out, n);
    k_fused<false><<<layer_blocks, 1024, 0, stream>>>(hb_b, ro, ssrc, Bp + 2 * bpl,
            bias + 2 * D, xb, hb_a, fcW, fcb, out, n);
    k_fused<true><<<layer_blocks, 1024, 0, stream>>>(hb_a, ro, ssrc, Bp + 3 * bpl,
            bias + 3 * D, xb, hb_b, fcW, fcb, out, n);
}